// Round 8
// baseline (278.118 us; speedup 1.0000x reference)
//
#include <hip/hip_runtime.h>

// Fused actor-critic forward for S=256,B=1024,D=64,H=128,A=8.
// R8 = R6 verbatim + __launch_bounds__(256,4) ONLY (A/B test: R7 changed this
// AND bf16-carry together and produced inf; carry stays f32 here).
// Structure: weights never touch LDS (frag-ordered bf16 images in ws, prep
// kernel); 16KB LDS activation buffer (X->H1->H2->h); gate GEMMs barrier-free;
// gate math = carry algebra (4 exp2 + 2 rcp / elem) with prescaled biases.
// WRITE_SIZE ~17.4MB is the no-spill canary.

#define NROWS (256 * 1024)
#define HID 128
#define ACTD 8

// ws layout (bytes) — all weight images frag-ordered:
// chunk dst = (((ftile*KC + kc)*4 + ks)*16 + r)*16 ; lane addr = base +
// ((ftile*KC+kc)<<10) + ((lane>>4)<<8) + ((lane&15)<<4)
#define W1_OFF 0                  // [128f][64K]  KC=2, 16KB
#define W2_OFF 16384              // [128][128]   KC=4, 32KB
#define WI_OFF 49152              // wih rows 0..127
#define WG_OFF 81920              // wih rows 256..383
#define WO_OFF 114688             // wih rows 384..511
#define PSTR 147456               // per-path stride
#define HEAD_OFF (2 * PSTR)       // actor [mw;lw] 4KB, critic [vw;0] 4KB
#define GB_OFF (HEAD_OFF + 8192)  // prescaled gate biases, 384 f32 per path

#define NEG_L (-1.4426950408889634f)
#define TWO_L (2.8853900817779268f)

typedef __attribute__((ext_vector_type(8))) short s16x8;
typedef __attribute__((ext_vector_type(4))) float fx4;
typedef __attribute__((ext_vector_type(2))) unsigned int u32x2;
typedef __attribute__((ext_vector_type(4))) unsigned int u32x4;

__device__ __forceinline__ unsigned int cvtpk(float lo, float hi) {
  unsigned int r;
  asm("v_cvt_pk_bf16_f32 %0, %1, %2" : "=v"(r) : "v"(lo), "v"(hi));
  return r;
}

__device__ __forceinline__ float ex2(float x) {
  return __builtin_amdgcn_exp2f(x);
}
__device__ __forceinline__ float frcp(float x) {
  return __builtin_amdgcn_rcpf(x);
}

// 8 bf16 from swizzled LDS tile: row-major 2^rowsh B/row, chunk XOR (row&7)<<4
__device__ __forceinline__ s16x8 frag_ld(const unsigned short* base, int row,
                                         int kbyte, int rowsh) {
  int byte = (row << rowsh) + (kbyte ^ ((row & 7) << 4));
  return *(const s16x8*)((const char*)base + byte);
}

__device__ __forceinline__ void zacc(fx4 acc[4][2]) {
#pragma unroll
  for (int j = 0; j < 4; ++j)
#pragma unroll
    for (int i = 0; i < 2; ++i) acc[j][i] = fx4{0.f, 0.f, 0.f, 0.f};
}

// init acc with per-feature bias (broadcast across row tiles)
__device__ __forceinline__ void bacc(fx4 acc[4][2], const float* __restrict__ b,
                                     int fb, int g4) {
#pragma unroll
  for (int it = 0; it < 2; ++it) {
    fx4 bv = *(const fx4*)(b + fb + it * 16 + g4);
#pragma unroll
    for (int jt = 0; jt < 4; ++jt) acc[jt][it] = bv;
  }
}

// Feature-split GEMM, weights straight from global frag-ordered image.
// Wave wv -> feats wv*32..+31, rows 0..63 from swizzled abuf.
template <int KC, int ASH>
__device__ __forceinline__ void gemm_g(const char* __restrict__ wimg,
                                       const unsigned short* at, int wv,
                                       int lane, fx4 acc[4][2]) {
  const int l15 = lane & 15;
  const int kb0 = (lane >> 4) << 4;
  const int woff = ((lane >> 4) << 8) + (l15 << 4);
#pragma unroll
  for (int kc = 0; kc < KC; ++kc) {
    int kbyte = kc * 64 + kb0;
    s16x8 w0 = *(const s16x8*)(wimg + (((wv * 2 + 0) * KC + kc) << 10) + woff);
    s16x8 w1 = *(const s16x8*)(wimg + (((wv * 2 + 1) * KC + kc) << 10) + woff);
#pragma unroll
    for (int jt = 0; jt < 4; ++jt) {
      s16x8 a = frag_ld(at, jt * 16 + l15, kbyte, ASH);
      acc[jt][0] = __builtin_amdgcn_mfma_f32_16x16x32_bf16(w0, a, acc[jt][0], 0, 0, 0);
      acc[jt][1] = __builtin_amdgcn_mfma_f32_16x16x32_bf16(w1, a, acc[jt][1], 0, 0, 0);
    }
  }
}

// acc (bias already in) -> relu -> bf16 -> swizzled abuf [64][128f] 256B rows
__device__ __forceinline__ void epi_relu(fx4 acc[4][2], unsigned short* obuf,
                                         int fb, int lane) {
  const int g4 = (lane >> 4) << 2;
  const int l15 = lane & 15;
  char* ob = (char*)obuf;
#pragma unroll
  for (int it = 0; it < 2; ++it) {
    int n0 = fb + it * 16 + g4;
#pragma unroll
    for (int jt = 0; jt < 4; ++jt) {
      fx4 v = acc[jt][it];
#pragma unroll
      for (int r = 0; r < 4; ++r) v[r] = fmaxf(v[r], 0.0f);
      u32x2 u;
      u[0] = cvtpk(v[0], v[1]);
      u[1] = cvtpk(v[2], v[3]);
      int m = jt * 16 + l15;
      *(u32x2*)(ob + (m << 8) + ((n0 * 2) ^ ((m & 7) << 4))) = u;
    }
  }
}

// ---------------- prep: weights -> bf16 frag-ordered images ----------------
__global__ void prep_weights(const float* __restrict__ aw1,
                             const float* __restrict__ aw2,
                             const float* __restrict__ awih,
                             const float* __restrict__ cw1,
                             const float* __restrict__ cw2,
                             const float* __restrict__ cwih,
                             const float* __restrict__ mw,
                             const float* __restrict__ lw,
                             const float* __restrict__ vw,
                             const float* __restrict__ abih,
                             const float* __restrict__ abhh,
                             const float* __restrict__ cbih,
                             const float* __restrict__ cbhh,
                             char* __restrict__ ws) {
  int y = blockIdx.y;
  int idx = blockIdx.x * 256 + threadIdx.x;
  if (y >= 12) {  // prescaled gate biases: [pgi(128); pgg(128); pgo(128)]
    if (idx < 384) {
      float* dst = (float*)(ws + GB_OFF + (size_t)(y - 12) * 1536);
      const float* b0 = (y == 12) ? abih : cbih;
      const float* b1 = (y == 12) ? abhh : cbhh;
      int sect = idx >> 7, f = idx & 127;
      int srow = (sect == 0) ? f : (sect == 1) ? 256 + f : 384 + f;
      float scale = (sect == 1) ? TWO_L : NEG_L;
      dst[idx] = scale * (b0[srow] + b1[srow]);
    }
    return;
  }
  if (y >= 10) {  // head images: 16 rows x 128 K, frag-ordered (ftile=0)
    if (idx >= 256) return;
    int row = idx >> 4, c16 = idx & 15, kc = c16 >> 2, ks = c16 & 3;
    fx4 v0 = {0.f, 0.f, 0.f, 0.f}, v1 = v0;
    if (y == 10) {
      const float* src = (row < 8) ? (mw + (size_t)row * HID + c16 * 8)
                                   : (lw + (size_t)(row - 8) * HID + c16 * 8);
      v0 = ((const fx4*)src)[0];
      v1 = ((const fx4*)src)[1];
    } else if (row == 0) {
      const float* src = vw + c16 * 8;
      v0 = ((const fx4*)src)[0];
      v1 = ((const fx4*)src)[1];
    }
    u32x4 u;
    u[0] = cvtpk(v0[0], v0[1]);
    u[1] = cvtpk(v0[2], v0[3]);
    u[2] = cvtpk(v1[0], v1[1]);
    u[3] = cvtpk(v1[2], v1[3]);
    int dst = ((kc * 4 + ks) * 16 + row) * 16;
    *(u32x4*)(ws + HEAD_OFF + (size_t)(y - 10) * 4096 + dst) = u;
    return;
  }
  const float* src;
  int nch, ksh, KC, off;
  switch (y) {
    case 0:  src = aw1;              nch = 1024; ksh = 3; KC = 2; off = W1_OFF;        break;
    case 1:  src = aw2;              nch = 2048; ksh = 4; KC = 4; off = W2_OFF;        break;
    case 2:  src = awih;             nch = 2048; ksh = 4; KC = 4; off = WI_OFF;        break;
    case 3:  src = awih + 256 * HID; nch = 2048; ksh = 4; KC = 4; off = WG_OFF;        break;
    case 4:  src = awih + 384 * HID; nch = 2048; ksh = 4; KC = 4; off = WO_OFF;        break;
    case 5:  src = cw1;              nch = 1024; ksh = 3; KC = 2; off = PSTR + W1_OFF; break;
    case 6:  src = cw2;              nch = 2048; ksh = 4; KC = 4; off = PSTR + W2_OFF; break;
    case 7:  src = cwih;             nch = 2048; ksh = 4; KC = 4; off = PSTR + WI_OFF; break;
    case 8:  src = cwih + 256 * HID; nch = 2048; ksh = 4; KC = 4; off = PSTR + WG_OFF; break;
    default: src = cwih + 384 * HID; nch = 2048; ksh = 4; KC = 4; off = PSTR + WO_OFF; break;
  }
  if (idx >= nch) return;
  int row = idx >> ksh;
  int c16 = idx & ((1 << ksh) - 1);
  int b2 = row >> 4, r = row & 15, kc = c16 >> 2, ks = c16 & 3;
  const fx4* gp = (const fx4*)(src + (size_t)idx * 8);
  fx4 v0 = gp[0], v1 = gp[1];
  u32x4 u;
  u[0] = cvtpk(v0[0], v0[1]);
  u[1] = cvtpk(v0[2], v0[3]);
  u[2] = cvtpk(v1[0], v1[1]);
  u[3] = cvtpk(v1[2], v1[3]);
  int dst = (((b2 * KC + kc) * 4 + ks) * 16 + r) * 16;
  *(u32x4*)(ws + off + dst) = u;
}

// ---------------- main fused kernel: one path x 64 rows per block ----------
__global__ __launch_bounds__(256, 4) void fused_ac(
    const float* __restrict__ state, const float* __restrict__ ab1,
    const float* __restrict__ ab2, const float* __restrict__ cb1,
    const float* __restrict__ cb2, const float* __restrict__ mb,
    const float* __restrict__ lb, const float* __restrict__ vb,
    const char* __restrict__ ws, float* __restrict__ outp) {
  __shared__ __align__(16) unsigned short abuf[8192];  // 16KB: X->H1->H2->h

  const int tid = threadIdx.x;
  const int lane = tid & 63;
  const int wv = tid >> 6;
  const int l15 = lane & 15;
  const int g4 = (lane >> 4) << 2;
  const int kb0 = (lane >> 4) << 4;
  const int fb = wv << 5;  // feature band base
  const int path = blockIdx.x >> 12;
  const int rbase = (blockIdx.x & 4095) << 6;  // 64 rows per block

  const char* wsp = ws + (size_t)path * PSTR;
  const float* b1 = path ? cb1 : ab1;
  const float* b2 = path ? cb2 : ab2;
  const float* gb = (const float*)(ws + GB_OFF + (size_t)path * 1536);
  const char* himg = ws + HEAD_OFF + (size_t)path * 4096;

  float* meanp = outp;
  float* stdp = outp + (size_t)NROWS * ACTD;
  float* valp = outp + (size_t)NROWS * ACTD * 2;

  // stage X [64][64] f32 -> bf16 swizzled (128B rows) into abuf
  {
    const float* xg = state + (size_t)rbase * 64;
    char* ab = (char*)abuf;
#pragma unroll
    for (int i = 0; i < 2; ++i) {
      int idx = tid + i * 256;
      int r = idx >> 3, c = idx & 7;
      const fx4* gp = (const fx4*)(xg + idx * 8);
      fx4 v0 = gp[0], v1 = gp[1];
      u32x4 u;
      u[0] = cvtpk(v0[0], v0[1]);
      u[1] = cvtpk(v0[2], v0[3]);
      u[2] = cvtpk(v1[0], v1[1]);
      u[3] = cvtpk(v1[2], v1[3]);
      *(u32x4*)(ab + r * 128 + ((c << 4) ^ ((r & 7) << 4))) = u;
    }
  }
  __syncthreads();

  fx4 acc[4][2];
  bacc(acc, b1, fb, g4);
  gemm_g<2, 7>(wsp + W1_OFF, abuf, wv, lane, acc);  // H1 = X*W1^T + b1
  __syncthreads();
  epi_relu(acc, abuf, fb, lane);
  __syncthreads();

  bacc(acc, b2, fb, g4);
  gemm_g<4, 8>(wsp + W2_OFF, abuf, wv, lane, acc);  // H2 = H1*W2^T + b2
  __syncthreads();
  epi_relu(acc, abuf, fb, lane);
  __syncthreads();

  // gate GEMMs: abuf read-only -> no barriers between them
  fx4 carry[4][2];  // e^{-i} -> e^{2c}
  zacc(acc);
  gemm_g<4, 8>(wsp + WI_OFF, abuf, wv, lane, acc);  // i gate
#pragma unroll
  for (int it = 0; it < 2; ++it) {
    fx4 pv = *(const fx4*)(gb + fb + it * 16 + g4);
#pragma unroll
    for (int jt = 0; jt < 4; ++jt)
#pragma unroll
      for (int r = 0; r < 4; ++r)
        carry[jt][it][r] = ex2(fmaf(acc[jt][it][r], NEG_L, pv[r]));  // e^{-i}
  }

  zacc(acc);
  gemm_g<4, 8>(wsp + WG_OFF, abuf, wv, lane, acc);  // g gate
#pragma unroll
  for (int it = 0; it < 2; ++it) {
    fx4 pv = *(const fx4*)(gb + 128 + fb + it * 16 + g4);
#pragma unroll
    for (int jt = 0; jt < 4; ++jt)
#pragma unroll
      for (int r = 0; r < 4; ++r) {
        float Eg = ex2(fmaf(acc[jt][it][r], TWO_L, pv[r]));  // e^{2g}
        float c = (Eg - 1.0f) * frcp((Eg + 1.0f) * (carry[jt][it][r] + 1.0f));
        carry[jt][it][r] = ex2(c * TWO_L);  // e^{2c}
      }
  }

  zacc(acc);
  gemm_g<4, 8>(wsp + WO_OFF, abuf, wv, lane, acc);  // o gate
  __syncthreads();  // all gate reads of abuf done; safe to overwrite with h
  {
    char* ob = (char*)abuf;
#pragma unroll
    for (int it = 0; it < 2; ++it) {
      fx4 pv = *(const fx4*)(gb + 256 + fb + it * 16 + g4);
      int n0 = fb + it * 16 + g4;
#pragma unroll
      for (int jt = 0; jt < 4; ++jt) {
        fx4 h;
#pragma unroll
        for (int r = 0; r < 4; ++r) {
          float Eo = ex2(fmaf(acc[jt][it][r], NEG_L, pv[r]));  // e^{-o}
          float Ec = carry[jt][it][r];
          h[r] = (Ec - 1.0f) * frcp((Ec + 1.0f) * (Eo + 1.0f));
        }
        u32x2 u;
        u[0] = cvtpk(h[0], h[1]);
        u[1] = cvtpk(h[2], h[3]);
        int m = jt * 16 + l15;
        *(u32x2*)(ob + (m << 8) + ((n0 * 2) ^ ((m & 7) << 4))) = u;
      }
    }
  }
  __syncthreads();

  // head GEMM: wave wv -> rows wv*16..+15; head weights from global image
  fx4 ha = fx4{0.f, 0.f, 0.f, 0.f};
  const int woff = ((lane >> 4) << 8) + (l15 << 4);
#pragma unroll
  for (int kc = 0; kc < 4; ++kc) {
    s16x8 w = *(const s16x8*)(himg + (kc << 10) + woff);
    s16x8 a = frag_ld(abuf, (wv << 4) + l15, kc * 64 + kb0, 8);
    ha = __builtin_amdgcn_mfma_f32_16x16x32_bf16(w, a, ha, 0, 0, 0);
  }

  int m = rbase + (wv << 4) + l15;
  if (path == 0) {
    if (g4 < 8) {
      fx4 v = ha + *(const fx4*)(mb + g4);
      *(fx4*)(meanp + (size_t)m * ACTD + g4) = v;
    } else {
      fx4 v;
#pragma unroll
      for (int r = 0; r < 4; ++r) v[r] = __expf(ha[r] + lb[g4 - 8 + r]);
      *(fx4*)(stdp + (size_t)m * ACTD + (g4 - 8)) = v;
    }
  } else if (g4 == 0) {
    valp[m] = ha[0] + vb[0];
  }
}

extern "C" void kernel_launch(void* const* d_in, const int* in_sizes, int n_in,
                              void* d_out, int out_size, void* d_ws,
                              size_t ws_size, hipStream_t stream) {
  (void)in_sizes; (void)n_in; (void)ws_size; (void)out_size;
  const float* state = (const float*)d_in[0];
  const float* aw1 = (const float*)d_in[1];
  const float* ab1 = (const float*)d_in[2];
  const float* aw2 = (const float*)d_in[3];
  const float* ab2 = (const float*)d_in[4];
  const float* cw1 = (const float*)d_in[5];
  const float* cb1 = (const float*)d_in[6];
  const float* cw2 = (const float*)d_in[7];
  const float* cb2 = (const float*)d_in[8];
  const float* awih = (const float*)d_in[9];
  // d_in[10] = a_whh (unused: zero-state LSTM)
  const float* abih = (const float*)d_in[11];
  const float* abhh = (const float*)d_in[12];
  const float* cwih = (const float*)d_in[13];
  // d_in[14] = c_whh (unused)
  const float* cbih = (const float*)d_in[15];
  const float* cbhh = (const float*)d_in[16];
  const float* mw = (const float*)d_in[17];
  const float* mb = (const float*)d_in[18];
  const float* lw = (const float*)d_in[19];
  const float* lb = (const float*)d_in[20];
  const float* vw = (const float*)d_in[21];
  const float* vb = (const float*)d_in[22];
  char* ws = (char*)d_ws;

  prep_weights<<<dim3(8, 14), 256, 0, stream>>>(
      aw1, aw2, awih, cw1, cw2, cwih, mw, lw, vw, abih, abhh, cbih, cbhh, ws);
  fused_ac<<<8192, 256, 0, stream>>>(state, ab1, ab2, cb1, cb2, mb, lb, vb, ws,
                                     (float*)d_out);
}

// Round 9
// 120.057 us; speedup vs baseline: 2.3165x; 2.3165x over previous
//
#include <hip/hip_runtime.h>

// Fused actor-critic forward for S=256,B=1024,D=64,H=128,A=8.
// R9 = R6 + latency attack at fixed occupancy (3 waves/SIMD is AGPR-limited:
// 84 VGPR + ~64 AGPR = 148/wave on the unified gfx950 file; R8 proved the
// 4-wave budget spills 731MB). Changes vs R6:
//  (a) double-buffered activations (abuf: X->H2, hbuf: H1->h) -> 6 barriers
//      become 4 (no write-after-read barriers),
//  (b) next-phase weight fragments (kc0,kc1 pairs; all 4 head loads) are
//      prefetched into VGPRs BEFORE each barrier — hides the ~200cyc L2
//      latency under the barrier + epilogue.
// Structure: weights never touch LDS (frag-ordered bf16 images in ws);
// gate GEMMs barrier-free; gate math = 4 exp2 + 2 rcp / elem, prescaled bias.

#define NROWS (256 * 1024)
#define HID 128
#define ACTD 8

// ws layout (bytes) — all weight images frag-ordered:
// chunk dst = (((ftile*KC + kc)*4 + ks)*16 + r)*16 ; lane addr = base +
// ((ftile*KC+kc)<<10) + ((lane>>4)<<8) + ((lane&15)<<4)
#define W1_OFF 0                  // [128f][64K]  KC=2, 16KB
#define W2_OFF 16384              // [128][128]   KC=4, 32KB
#define WI_OFF 49152              // wih rows 0..127
#define WG_OFF 81920              // wih rows 256..383
#define WO_OFF 114688             // wih rows 384..511
#define PSTR 147456               // per-path stride
#define HEAD_OFF (2 * PSTR)       // actor [mw;lw] 4KB, critic [vw;0] 4KB
#define GB_OFF (HEAD_OFF + 8192)  // prescaled gate biases, 384 f32 per path

#define NEG_L (-1.4426950408889634f)
#define TWO_L (2.8853900817779268f)

typedef __attribute__((ext_vector_type(8))) short s16x8;
typedef __attribute__((ext_vector_type(4))) float fx4;
typedef __attribute__((ext_vector_type(2))) unsigned int u32x2;
typedef __attribute__((ext_vector_type(4))) unsigned int u32x4;

__device__ __forceinline__ unsigned int cvtpk(float lo, float hi) {
  unsigned int r;
  asm("v_cvt_pk_bf16_f32 %0, %1, %2" : "=v"(r) : "v"(lo), "v"(hi));
  return r;
}
__device__ __forceinline__ float ex2(float x) {
  return __builtin_amdgcn_exp2f(x);
}
__device__ __forceinline__ float frcp(float x) {
  return __builtin_amdgcn_rcpf(x);
}

// 8 bf16 from swizzled LDS tile: row-major 2^rowsh B/row, chunk XOR (row&7)<<4
__device__ __forceinline__ s16x8 frag_ld(const unsigned short* base, int row,
                                         int kbyte, int rowsh) {
  int byte = (row << rowsh) + (kbyte ^ ((row & 7) << 4));
  return *(const s16x8*)((const char*)base + byte);
}

struct wpair {
  s16x8 w0, w1;
};
// load one (kc) weight-fragment pair from a frag-ordered image
template <int KC>
__device__ __forceinline__ wpair wload(const char* __restrict__ wimg, int wv,
                                       int kc, int woff) {
  wpair p;
  p.w0 = *(const s16x8*)(wimg + (((wv * 2 + 0) * KC + kc) << 10) + woff);
  p.w1 = *(const s16x8*)(wimg + (((wv * 2 + 1) * KC + kc) << 10) + woff);
  return p;
}

// one kc step: 4 row-tiles of MFMA against a prefetched weight pair
template <int ASH>
__device__ __forceinline__ void gemm_kc(const wpair& p,
                                        const unsigned short* at, int kbyte,
                                        int l15, fx4 acc[4][2]) {
#pragma unroll
  for (int jt = 0; jt < 4; ++jt) {
    s16x8 a = frag_ld(at, jt * 16 + l15, kbyte, ASH);
    acc[jt][0] = __builtin_amdgcn_mfma_f32_16x16x32_bf16(p.w0, a, acc[jt][0], 0, 0, 0);
    acc[jt][1] = __builtin_amdgcn_mfma_f32_16x16x32_bf16(p.w1, a, acc[jt][1], 0, 0, 0);
  }
}

__device__ __forceinline__ void zacc(fx4 acc[4][2]) {
#pragma unroll
  for (int j = 0; j < 4; ++j)
#pragma unroll
    for (int i = 0; i < 2; ++i) acc[j][i] = fx4{0.f, 0.f, 0.f, 0.f};
}
__device__ __forceinline__ void bacc(fx4 acc[4][2], const float* __restrict__ b,
                                     int fb, int g4) {
#pragma unroll
  for (int it = 0; it < 2; ++it) {
    fx4 bv = *(const fx4*)(b + fb + it * 16 + g4);
#pragma unroll
    for (int jt = 0; jt < 4; ++jt) acc[jt][it] = bv;
  }
}

// acc (bias already in) -> relu -> bf16 -> swizzled buf [64][128f] 256B rows
__device__ __forceinline__ void epi_relu(fx4 acc[4][2], unsigned short* obuf,
                                         int fb, int lane) {
  const int g4 = (lane >> 4) << 2;
  const int l15 = lane & 15;
  char* ob = (char*)obuf;
#pragma unroll
  for (int it = 0; it < 2; ++it) {
    int n0 = fb + it * 16 + g4;
#pragma unroll
    for (int jt = 0; jt < 4; ++jt) {
      fx4 v = acc[jt][it];
#pragma unroll
      for (int r = 0; r < 4; ++r) v[r] = fmaxf(v[r], 0.0f);
      u32x2 u;
      u[0] = cvtpk(v[0], v[1]);
      u[1] = cvtpk(v[2], v[3]);
      int m = jt * 16 + l15;
      *(u32x2*)(ob + (m << 8) + ((n0 * 2) ^ ((m & 7) << 4))) = u;
    }
  }
}

// ---------------- prep: weights -> bf16 frag-ordered images ----------------
__global__ void prep_weights(const float* __restrict__ aw1,
                             const float* __restrict__ aw2,
                             const float* __restrict__ awih,
                             const float* __restrict__ cw1,
                             const float* __restrict__ cw2,
                             const float* __restrict__ cwih,
                             const float* __restrict__ mw,
                             const float* __restrict__ lw,
                             const float* __restrict__ vw,
                             const float* __restrict__ abih,
                             const float* __restrict__ abhh,
                             const float* __restrict__ cbih,
                             const float* __restrict__ cbhh,
                             char* __restrict__ ws) {
  int y = blockIdx.y;
  int idx = blockIdx.x * 256 + threadIdx.x;
  if (y >= 12) {  // prescaled gate biases: [pgi(128); pgg(128); pgo(128)]
    if (idx < 384) {
      float* dst = (float*)(ws + GB_OFF + (size_t)(y - 12) * 1536);
      const float* b0 = (y == 12) ? abih : cbih;
      const float* b1 = (y == 12) ? abhh : cbhh;
      int sect = idx >> 7, f = idx & 127;
      int srow = (sect == 0) ? f : (sect == 1) ? 256 + f : 384 + f;
      float scale = (sect == 1) ? TWO_L : NEG_L;
      dst[idx] = scale * (b0[srow] + b1[srow]);
    }
    return;
  }
  if (y >= 10) {  // head images: 16 rows x 128 K, frag-ordered (ftile=0)
    if (idx >= 256) return;
    int row = idx >> 4, c16 = idx & 15, kc = c16 >> 2, ks = c16 & 3;
    fx4 v0 = {0.f, 0.f, 0.f, 0.f}, v1 = v0;
    if (y == 10) {
      const float* src = (row < 8) ? (mw + (size_t)row * HID + c16 * 8)
                                   : (lw + (size_t)(row - 8) * HID + c16 * 8);
      v0 = ((const fx4*)src)[0];
      v1 = ((const fx4*)src)[1];
    } else if (row == 0) {
      const float* src = vw + c16 * 8;
      v0 = ((const fx4*)src)[0];
      v1 = ((const fx4*)src)[1];
    }
    u32x4 u;
    u[0] = cvtpk(v0[0], v0[1]);
    u[1] = cvtpk(v0[2], v0[3]);
    u[2] = cvtpk(v1[0], v1[1]);
    u[3] = cvtpk(v1[2], v1[3]);
    int dst = ((kc * 4 + ks) * 16 + row) * 16;
    *(u32x4*)(ws + HEAD_OFF + (size_t)(y - 10) * 4096 + dst) = u;
    return;
  }
  const float* src;
  int nch, ksh, KC, off;
  switch (y) {
    case 0:  src = aw1;              nch = 1024; ksh = 3; KC = 2; off = W1_OFF;        break;
    case 1:  src = aw2;              nch = 2048; ksh = 4; KC = 4; off = W2_OFF;        break;
    case 2:  src = awih;             nch = 2048; ksh = 4; KC = 4; off = WI_OFF;        break;
    case 3:  src = awih + 256 * HID; nch = 2048; ksh = 4; KC = 4; off = WG_OFF;        break;
    case 4:  src = awih + 384 * HID; nch = 2048; ksh = 4; KC = 4; off = WO_OFF;        break;
    case 5:  src = cw1;              nch = 1024; ksh = 3; KC = 2; off = PSTR + W1_OFF; break;
    case 6:  src = cw2;              nch = 2048; ksh = 4; KC = 4; off = PSTR + W2_OFF; break;
    case 7:  src = cwih;             nch = 2048; ksh = 4; KC = 4; off = PSTR + WI_OFF; break;
    case 8:  src = cwih + 256 * HID; nch = 2048; ksh = 4; KC = 4; off = PSTR + WG_OFF; break;
    default: src = cwih + 384 * HID; nch = 2048; ksh = 4; KC = 4; off = PSTR + WO_OFF; break;
  }
  if (idx >= nch) return;
  int row = idx >> ksh;
  int c16 = idx & ((1 << ksh) - 1);
  int b2 = row >> 4, r = row & 15, kc = c16 >> 2, ks = c16 & 3;
  const fx4* gp = (const fx4*)(src + (size_t)idx * 8);
  fx4 v0 = gp[0], v1 = gp[1];
  u32x4 u;
  u[0] = cvtpk(v0[0], v0[1]);
  u[1] = cvtpk(v0[2], v0[3]);
  u[2] = cvtpk(v1[0], v1[1]);
  u[3] = cvtpk(v1[2], v1[3]);
  int dst = (((b2 * KC + kc) * 4 + ks) * 16 + r) * 16;
  *(u32x4*)(ws + off + dst) = u;
}

// ---------------- main fused kernel: one path x 64 rows per block ----------
__global__ __launch_bounds__(256, 3) void fused_ac(
    const float* __restrict__ state, const float* __restrict__ ab1,
    const float* __restrict__ ab2, const float* __restrict__ cb1,
    const float* __restrict__ cb2, const float* __restrict__ mb,
    const float* __restrict__ lb, const float* __restrict__ vb,
    const char* __restrict__ ws, float* __restrict__ outp) {
  __shared__ __align__(16) unsigned short abuf[8192];  // 16KB: X -> H2
  __shared__ __align__(16) unsigned short hbuf[8192];  // 16KB: H1 -> h

  const int tid = threadIdx.x;
  const int lane = tid & 63;
  const int wv = tid >> 6;
  const int l15 = lane & 15;
  const int g4 = (lane >> 4) << 2;
  const int kb0 = (lane >> 4) << 4;
  const int woff = ((lane >> 4) << 8) + (l15 << 4);
  const int fb = wv << 5;  // feature band base
  const int path = blockIdx.x >> 12;
  const int rbase = (blockIdx.x & 4095) << 6;  // 64 rows per block

  const char* wsp = ws + (size_t)path * PSTR;
  const float* b1 = path ? cb1 : ab1;
  const float* b2 = path ? cb2 : ab2;
  const float* gb = (const float*)(ws + GB_OFF + (size_t)path * 1536);
  const char* himg = ws + HEAD_OFF + (size_t)path * 4096;

  float* meanp = outp;
  float* stdp = outp + (size_t)NROWS * ACTD;
  float* valp = outp + (size_t)NROWS * ACTD * 2;

  // prefetch ALL of W1 (KC=2) while staging X
  wpair w1a = wload<2>(wsp + W1_OFF, wv, 0, woff);
  wpair w1b = wload<2>(wsp + W1_OFF, wv, 1, woff);

  // stage X [64][64] f32 -> bf16 swizzled (128B rows) into abuf
  {
    const float* xg = state + (size_t)rbase * 64;
    char* ab = (char*)abuf;
#pragma unroll
    for (int i = 0; i < 2; ++i) {
      int idx = tid + i * 256;
      int r = idx >> 3, c = idx & 7;
      const fx4* gp = (const fx4*)(xg + idx * 8);
      fx4 v0 = gp[0], v1 = gp[1];
      u32x4 u;
      u[0] = cvtpk(v0[0], v0[1]);
      u[1] = cvtpk(v0[2], v0[3]);
      u[2] = cvtpk(v1[0], v1[1]);
      u[3] = cvtpk(v1[2], v1[3]);
      *(u32x4*)(ab + r * 128 + ((c << 4) ^ ((r & 7) << 4))) = u;
    }
  }
  __syncthreads();  // (1) X visible

  fx4 acc[4][2];
  bacc(acc, b1, fb, g4);
  gemm_kc<7>(w1a, abuf, 0 + kb0, l15, acc);   // H1 = X*W1^T + b1
  gemm_kc<7>(w1b, abuf, 64 + kb0, l15, acc);
  // prefetch W2 kc0,kc1; epilogue H1 -> hbuf (no WAR: different buffer)
  wpair w2a = wload<4>(wsp + W2_OFF, wv, 0, woff);
  wpair w2b = wload<4>(wsp + W2_OFF, wv, 1, woff);
  epi_relu(acc, hbuf, fb, lane);
  __syncthreads();  // (2) H1 visible

  bacc(acc, b2, fb, g4);
  gemm_kc<8>(w2a, hbuf, 0 + kb0, l15, acc);   // H2 = H1*W2^T + b2
  gemm_kc<8>(w2b, hbuf, 64 + kb0, l15, acc);
  {
    wpair p = wload<4>(wsp + W2_OFF, wv, 2, woff);
    gemm_kc<8>(p, hbuf, 128 + kb0, l15, acc);
  }
  {
    wpair p = wload<4>(wsp + W2_OFF, wv, 3, woff);
    gemm_kc<8>(p, hbuf, 192 + kb0, l15, acc);
  }
  // prefetch WI kc0,kc1; epilogue H2 -> abuf (X fully consumed pre-barrier 2)
  wpair wia = wload<4>(wsp + WI_OFF, wv, 0, woff);
  wpair wib = wload<4>(wsp + WI_OFF, wv, 1, woff);
  epi_relu(acc, abuf, fb, lane);
  __syncthreads();  // (3) H2 visible

  // ---- gate GEMMs: abuf read-only, no barriers between them ----
  fx4 carry[4][2];  // e^{-i} -> e^{2c}
  zacc(acc);
  gemm_kc<8>(wia, abuf, 0 + kb0, l15, acc);   // i gate
  gemm_kc<8>(wib, abuf, 64 + kb0, l15, acc);
  {
    wpair p = wload<4>(wsp + WI_OFF, wv, 2, woff);
    gemm_kc<8>(p, abuf, 128 + kb0, l15, acc);
  }
  {
    wpair p = wload<4>(wsp + WI_OFF, wv, 3, woff);
    gemm_kc<8>(p, abuf, 192 + kb0, l15, acc);
  }
#pragma unroll
  for (int it = 0; it < 2; ++it) {
    fx4 pv = *(const fx4*)(gb + fb + it * 16 + g4);
#pragma unroll
    for (int jt = 0; jt < 4; ++jt)
#pragma unroll
      for (int r = 0; r < 4; ++r)
        carry[jt][it][r] = ex2(fmaf(acc[jt][it][r], NEG_L, pv[r]));  // e^{-i}
  }

  zacc(acc);
#pragma unroll
  for (int kc = 0; kc < 4; ++kc) {
    wpair p = wload<4>(wsp + WG_OFF, wv, kc, woff);
    gemm_kc<8>(p, abuf, kc * 64 + kb0, l15, acc);  // g gate
  }
#pragma unroll
  for (int it = 0; it < 2; ++it) {
    fx4 pv = *(const fx4*)(gb + 128 + fb + it * 16 + g4);
#pragma unroll
    for (int jt = 0; jt < 4; ++jt)
#pragma unroll
      for (int r = 0; r < 4; ++r) {
        float Eg = ex2(fmaf(acc[jt][it][r], TWO_L, pv[r]));  // e^{2g}
        float c = (Eg - 1.0f) * frcp((Eg + 1.0f) * (carry[jt][it][r] + 1.0f));
        carry[jt][it][r] = ex2(c * TWO_L);  // e^{2c}
      }
  }

  zacc(acc);
#pragma unroll
  for (int kc = 0; kc < 4; ++kc) {
    wpair p = wload<4>(wsp + WO_OFF, wv, kc, woff);
    gemm_kc<8>(p, abuf, kc * 64 + kb0, l15, acc);  // o gate
  }
  // prefetch all 4 head-weight fragments (16 rows -> single tile per kc)
  s16x8 hw0 = *(const s16x8*)(himg + (0 << 10) + woff);
  s16x8 hw1 = *(const s16x8*)(himg + (1 << 10) + woff);
  s16x8 hw2 = *(const s16x8*)(himg + (2 << 10) + woff);
  s16x8 hw3 = *(const s16x8*)(himg + (3 << 10) + woff);
  // h -> hbuf (hbuf's last reader was GEMM2, all waves past barrier 3)
  {
    char* ob = (char*)hbuf;
#pragma unroll
    for (int it = 0; it < 2; ++it) {
      fx4 pv = *(const fx4*)(gb + 256 + fb + it * 16 + g4);
      int n0 = fb + it * 16 + g4;
#pragma unroll
      for (int jt = 0; jt < 4; ++jt) {
        fx4 h;
#pragma unroll
        for (int r = 0; r < 4; ++r) {
          float Eo = ex2(fmaf(acc[jt][it][r], NEG_L, pv[r]));  // e^{-o}
          float Ec = carry[jt][it][r];
          h[r] = (Ec - 1.0f) * frcp((Ec + 1.0f) * (Eo + 1.0f));
        }
        u32x2 u;
        u[0] = cvtpk(h[0], h[1]);
        u[1] = cvtpk(h[2], h[3]);
        int m = jt * 16 + l15;
        *(u32x2*)(ob + (m << 8) + ((n0 * 2) ^ ((m & 7) << 4))) = u;
      }
    }
  }
  __syncthreads();  // (4) h visible

  // head GEMM: wave wv -> rows wv*16..+15
  fx4 ha = fx4{0.f, 0.f, 0.f, 0.f};
  ha = __builtin_amdgcn_mfma_f32_16x16x32_bf16(
      hw0, frag_ld(hbuf, (wv << 4) + l15, 0 + kb0, 8), ha, 0, 0, 0);
  ha = __builtin_amdgcn_mfma_f32_16x16x32_bf16(
      hw1, frag_ld(hbuf, (wv << 4) + l15, 64 + kb0, 8), ha, 0, 0, 0);
  ha = __builtin_amdgcn_mfma_f32_16x16x32_bf16(
      hw2, frag_ld(hbuf, (wv << 4) + l15, 128 + kb0, 8), ha, 0, 0, 0);
  ha = __builtin_amdgcn_mfma_f32_16x16x32_bf16(
      hw3, frag_ld(hbuf, (wv << 4) + l15, 192 + kb0, 8), ha, 0, 0, 0);

  int m = rbase + (wv << 4) + l15;
  if (path == 0) {
    if (g4 < 8) {
      fx4 v = ha + *(const fx4*)(mb + g4);
      *(fx4*)(meanp + (size_t)m * ACTD + g4) = v;
    } else {
      fx4 v;
#pragma unroll
      for (int r = 0; r < 4; ++r) v[r] = __expf(ha[r] + lb[g4 - 8 + r]);
      *(fx4*)(stdp + (size_t)m * ACTD + (g4 - 8)) = v;
    }
  } else if (g4 == 0) {
    valp[m] = ha[0] + vb[0];
  }
}

extern "C" void kernel_launch(void* const* d_in, const int* in_sizes, int n_in,
                              void* d_out, int out_size, void* d_ws,
                              size_t ws_size, hipStream_t stream) {
  (void)in_sizes; (void)n_in; (void)ws_size; (void)out_size;
  const float* state = (const float*)d_in[0];
  const float* aw1 = (const float*)d_in[1];
  const float* ab1 = (const float*)d_in[2];
  const float* aw2 = (const float*)d_in[3];
  const float* ab2 = (const float*)d_in[4];
  const float* cw1 = (const float*)d_in[5];
  const float* cb1 = (const float*)d_in[6];
  const float* cw2 = (const float*)d_in[7];
  const float* cb2 = (const float*)d_in[8];
  const float* awih = (const float*)d_in[9];
  // d_in[10] = a_whh (unused: zero-state LSTM)
  const float* abih = (const float*)d_in[11];
  const float* abhh = (const float*)d_in[12];
  const float* cwih = (const float*)d_in[13];
  // d_in[14] = c_whh (unused)
  const float* cbih = (const float*)d_in[15];
  const float* cbhh = (const float*)d_in[16];
  const float* mw = (const float*)d_in[17];
  const float* mb = (const float*)d_in[18];
  const float* lw = (const float*)d_in[19];
  const float* lb = (const float*)d_in[20];
  const float* vw = (const float*)d_in[21];
  const float* vb = (const float*)d_in[22];
  char* ws = (char*)d_ws;

  prep_weights<<<dim3(8, 14), 256, 0, stream>>>(
      aw1, aw2, awih, cw1, cw2, cwih, mw, lw, vw, abih, abhh, cbih, cbhh, ws);
  fused_ac<<<8192, 256, 0, stream>>>(state, ab1, ab2, cb1, cb2, mb, lb, vb, ws,
                                     (float*)d_out);
}